// Round 1
// baseline (2830.889 us; speedup 1.0000x reference)
//
#include <hip/hip_runtime.h>
#include <math.h>

#define EPSF 1e-8f
#define BIGF 1e30f

// ---------------------------------------------------------------------------
// Kernel 1: project vertices. Bit-exact replica of the numpy f32 op sequence:
//   v_cam = vertices @ R.T + t   -> ((vx*Ri0 + vy*Ri1) + vz*Ri2) + ti
//   uvw   = v_cam @ K.T          -> ((c0*Kj0 + c1*Kj1) + c2*Kj2)
//   xy    = uvw[:,:2] / z ,  z = v_cam[:,2]
// All ops via _rn intrinsics so hipcc cannot contract into FMA.
// ---------------------------------------------------------------------------
__global__ void k_prep_verts(const float* __restrict__ verts,
                             const float* __restrict__ Km,
                             const float* __restrict__ Rm,
                             const float* __restrict__ tv,
                             float* __restrict__ sx, float* __restrict__ sy,
                             float* __restrict__ sz, int nV)
{
    int v = blockIdx.x * blockDim.x + threadIdx.x;
    if (v >= nV) return;
    float vx = verts[3*v+0], vy = verts[3*v+1], vz = verts[3*v+2];
    float a;
    a = __fadd_rn(__fmul_rn(vx, Rm[0]), __fmul_rn(vy, Rm[1]));
    a = __fadd_rn(a, __fmul_rn(vz, Rm[2]));
    float c0 = __fadd_rn(a, tv[0]);
    a = __fadd_rn(__fmul_rn(vx, Rm[3]), __fmul_rn(vy, Rm[4]));
    a = __fadd_rn(a, __fmul_rn(vz, Rm[5]));
    float c1 = __fadd_rn(a, tv[1]);
    a = __fadd_rn(__fmul_rn(vx, Rm[6]), __fmul_rn(vy, Rm[7]));
    a = __fadd_rn(a, __fmul_rn(vz, Rm[8]));
    float c2 = __fadd_rn(a, tv[2]);

    float u0 = __fadd_rn(__fadd_rn(__fmul_rn(c0, Km[0]), __fmul_rn(c1, Km[1])),
                         __fmul_rn(c2, Km[2]));
    float u1 = __fadd_rn(__fadd_rn(__fmul_rn(c0, Km[3]), __fmul_rn(c1, Km[4])),
                         __fmul_rn(c2, Km[5]));
    sx[v] = __fdiv_rn(u0, c2);
    sy[v] = __fdiv_rn(u1, c2);
    sz[v] = c2;
}

// ---------------------------------------------------------------------------
// Kernel 2: per-face setup. Edge coefficients exactly as the reference forms
// them (single rounded subtractions), denom with the reference's mul/mul/add
// order, validity, and a conservative screen bbox (margin 0.5 px — rounded
// "inside" decisions can only move the boundary by ~1e-4 px).
// rec[3f+0] = {y12, x21, y20, x02}
// rec[3f+1] = {x2,  y2,  denom, z0}
// rec[3f+2] = {z1,  z2,  0, 0}
// box[f]    = {xmin, xmax, ymin, ymax}  (empty if invalid)
// ---------------------------------------------------------------------------
__global__ void k_prep_faces(const int* __restrict__ faces,
                             const float* __restrict__ sx, const float* __restrict__ sy,
                             const float* __restrict__ sz,
                             float4* __restrict__ rec, float4* __restrict__ box, int nF)
{
    int f = blockIdx.x * blockDim.x + threadIdx.x;
    if (f >= nF) return;
    int ia = faces[3*f+0], ib = faces[3*f+1], ic = faces[3*f+2];
    float x0 = sx[ia], y0 = sy[ia], z0 = sz[ia];
    float x1 = sx[ib], y1 = sy[ib], z1 = sz[ib];
    float x2 = sx[ic], y2 = sy[ic], z2 = sz[ic];
    float y12 = __fsub_rn(y1, y2);
    float x21 = __fsub_rn(x2, x1);
    float y20 = __fsub_rn(y2, y0);
    float x02 = __fsub_rn(x0, x2);
    float y02 = __fsub_rn(y0, y2);
    float dn  = __fadd_rn(__fmul_rn(y12, x02), __fmul_rn(x21, y02));
    bool valid = (fabsf(dn) > EPSF) && (fminf(fminf(z0, z1), z2) > EPSF);
    float bxmin, bxmax, bymin, bymax;
    if (valid) {
        bxmin = fminf(fminf(x0, x1), x2) - 0.5f;
        bxmax = fmaxf(fmaxf(x0, x1), x2) + 0.5f;
        bymin = fminf(fminf(y0, y1), y2) - 0.5f;
        bymax = fmaxf(fmaxf(y0, y1), y2) + 0.5f;
    } else {
        bxmin = BIGF; bxmax = -BIGF; bymin = BIGF; bymax = -BIGF;
    }
    rec[3*f+0] = make_float4(y12, x21, y20, x02);
    rec[3*f+1] = make_float4(x2, y2, dn, z0);
    rec[3*f+2] = make_float4(z1, z2, 0.0f, 0.0f);
    box[f]     = make_float4(bxmin, bxmax, bymin, bymax);
}

// ---------------------------------------------------------------------------
// Kernel 3: raster + shade. One wave per 8x8 pixel tile.
// Phase A: ballot-compacted LDS list of bbox-overlapping faces (ascending id).
// Phase B: z-test. Decisions bit-exact vs numpy:
//   n0/n1 sign pre-test (exactly equivalent to w>=0 after correctly-rounded
//   division) rejects ~97% of pairs before any division.
//   Winner rule: lexicographic min of (depth, face_id) == reference's chunked
//   argmin + strict-< merge.
// Phase C: shade winner only (bary normalization + 8-tap trilinear, relu'd).
// ---------------------------------------------------------------------------
__global__ __launch_bounds__(64) void k_raster(
    const float4* __restrict__ rec, const float4* __restrict__ box,
    const float* __restrict__ tex, const float* __restrict__ bgc,
    float* __restrict__ out, int nF, int W, int H)
{
    __shared__ unsigned short list[14336];   // nF=13776 fits
    int lane = threadIdx.x;
    int tx = lane & 7, ty = lane >> 3;
    int pxi = blockIdx.x * 8 + tx;
    int pyi = blockIdx.y * 8 + ty;
    float px = (float)pxi + 0.5f;
    float py = (float)pyi + 0.5f;
    float rx0 = (float)(blockIdx.x * 8) + 0.5f;
    float rx1 = rx0 + 7.0f;
    float ry0 = (float)(blockIdx.y * 8) + 0.5f;
    float ry1 = ry0 + 7.0f;

    int cnt = 0;
    for (int base = 0; base < nF; base += 64) {
        int f = base + lane;
        bool pass = false;
        if (f < nF) {
            float4 b = box[f];
            pass = (b.x <= rx1) && (b.y >= rx0) && (b.z <= ry1) && (b.w >= ry0);
        }
        unsigned long long m = __ballot(pass);
        if (pass) {
            int off = __popcll(m & ((1ull << lane) - 1ull));
            list[cnt + off] = (unsigned short)f;
        }
        cnt += (int)__popcll(m);
    }
    __syncthreads();

    float bd = BIGF;
    int bf = 0x7fffffff;
    for (int i = 0; i < cnt; ++i) {
        int f = (int)list[i];
        f = __builtin_amdgcn_readfirstlane(f);   // uniform -> scalar loads
        float4 r0 = rec[3*f+0];
        float4 r1 = rec[3*f+1];
        float4 r2 = rec[3*f+2];
        float dx = __fsub_rn(px, r1.x);
        float dy = __fsub_rn(py, r1.y);
        float n0 = __fadd_rn(__fmul_rn(r0.x, dx), __fmul_rn(r0.y, dy));
        float n1 = __fadd_rn(__fmul_rn(r0.z, dx), __fmul_rn(r0.w, dy));
        float dn = r1.z;
        bool dpos = dn > 0.0f;
        bool in0 = (n0 == 0.0f) || ((n0 > 0.0f) == dpos);  // == (n0/dn >= 0)
        bool in1 = (n1 == 0.0f) || ((n1 > 0.0f) == dpos);
        if (in0 && in1) {
            float w0 = __fdiv_rn(n0, dn);
            float w1 = __fdiv_rn(n1, dn);
            float w2 = __fsub_rn(__fsub_rn(1.0f, w0), w1);
            if (w2 >= 0.0f) {
                float a = __fdiv_rn(w0, r1.w);
                float b = __fdiv_rn(w1, r2.x);
                float c = __fdiv_rn(w2, r2.y);
                float iz = __fadd_rn(__fadd_rn(a, b), c);
                if (iz > EPSF) {
                    float d = __fdiv_rn(1.0f, iz);
                    if ((d < bd) || ((d == bd) && (f < bf))) { bd = d; bf = f; }
                }
            }
        }
    }

    // ---- shade winner ----
    float o0, o1, o2, oa;
    if (bd < BIGF) {
        int f = bf;
        float4 r0 = rec[3*f+0];
        float4 r1 = rec[3*f+1];
        float4 r2 = rec[3*f+2];
        float dx = __fsub_rn(px, r1.x);
        float dy = __fsub_rn(py, r1.y);
        float n0 = __fadd_rn(__fmul_rn(r0.x, dx), __fmul_rn(r0.y, dy));
        float n1 = __fadd_rn(__fmul_rn(r0.z, dx), __fmul_rn(r0.w, dy));
        float w0 = __fdiv_rn(n0, r1.z);
        float w1 = __fdiv_rn(n1, r1.z);
        float w2 = __fsub_rn(__fsub_rn(1.0f, w0), w1);
        float c0 = __fdiv_rn(w0, fmaxf(r1.w, EPSF));
        float c1 = __fdiv_rn(w1, fmaxf(r2.x, EPSF));
        float c2 = __fdiv_rn(w2, fmaxf(r2.y, EPSF));
        float s  = __fadd_rn(__fadd_rn(c0, c1), c2);
        s = fmaxf(s, EPSF);
        c0 = __fdiv_rn(c0, s);
        c1 = __fdiv_rn(c1, s);
        c2 = __fdiv_rn(c2, s);
        float p0 = __fmul_rn(fminf(fmaxf(c0, 0.0f), 1.0f), 7.0f);
        float p1 = __fmul_rn(fminf(fmaxf(c1, 0.0f), 1.0f), 7.0f);
        float p2 = __fmul_rn(fminf(fmaxf(c2, 0.0f), 1.0f), 7.0f);
        int i0 = (int)floorf(p0); i0 = i0 < 0 ? 0 : (i0 > 6 ? 6 : i0);
        int i1 = (int)floorf(p1); i1 = i1 < 0 ? 0 : (i1 > 6 ? 6 : i1);
        int i2 = (int)floorf(p2); i2 = i2 < 0 ? 0 : (i2 > 6 ? 6 : i2);
        float f0 = __fsub_rn(p0, (float)i0);
        float f1 = __fsub_rn(p1, (float)i1);
        float f2 = __fsub_rn(p2, (float)i2);
        const float* tb = tex + (size_t)f * (512 * 3);
        float a0 = 0.0f, a1 = 0.0f, a2 = 0.0f;
        #pragma unroll
        for (int d0 = 0; d0 < 2; ++d0) {
            float wx = d0 ? f0 : __fsub_rn(1.0f, f0);
            #pragma unroll
            for (int d1 = 0; d1 < 2; ++d1) {
                float wy = d1 ? f1 : __fsub_rn(1.0f, f1);
                #pragma unroll
                for (int d2 = 0; d2 < 2; ++d2) {
                    float wz = d2 ? f2 : __fsub_rn(1.0f, f2);
                    float w = __fmul_rn(__fmul_rn(wx, wy), wz);
                    int idx = (((i0 + d0) << 6) + ((i1 + d1) << 3) + (i2 + d2)) * 3;
                    a0 = __fadd_rn(a0, __fmul_rn(w, fmaxf(tb[idx + 0], 0.0f)));
                    a1 = __fadd_rn(a1, __fmul_rn(w, fmaxf(tb[idx + 1], 0.0f)));
                    a2 = __fadd_rn(a2, __fmul_rn(w, fmaxf(tb[idx + 2], 0.0f)));
                }
            }
        }
        o0 = a0; o1 = a1; o2 = a2; oa = 1.0f;
    } else {
        o0 = __fdiv_rn(bgc[0], 255.0f);
        o1 = __fdiv_rn(bgc[1], 255.0f);
        o2 = __fdiv_rn(bgc[2], 255.0f);
        oa = 0.0f;
    }
    if (pxi < W && pyi < H) {
        int p = pyi * W + pxi;
        out[3*p+0] = o0;
        out[3*p+1] = o1;
        out[3*p+2] = o2;
        out[(size_t)W*H*3 + p] = oa;
    }
}

// ---------------------------------------------------------------------------
extern "C" void kernel_launch(void* const* d_in, const int* in_sizes, int n_in,
                              void* d_out, int out_size, void* d_ws, size_t ws_size,
                              hipStream_t stream)
{
    const float* verts = (const float*)d_in[0];
    const float* Km    = (const float*)d_in[1];
    const float* Rm    = (const float*)d_in[2];
    const float* tv    = (const float*)d_in[3];
    const float* bgc   = (const float*)d_in[4];
    const float* tex   = (const float*)d_in[5];
    const int*   faces = (const int*)d_in[6];
    int nV = in_sizes[0] / 3;
    int nF = in_sizes[6] / 3;
    // out = rgb(H*W*3) + alpha(H*W)  ->  H = W = sqrt(out_size/4)
    int P = out_size / 4;
    int W = (int)(sqrt((double)P) + 0.5);
    int H = W;

    char* ws = (char*)d_ws;
    size_t o = 0;
    auto al = [](size_t x) { return (x + 255) & ~(size_t)255; };
    float*  sx  = (float*)(ws + o);  o = al(o + (size_t)nV * 4);
    float*  sy  = (float*)(ws + o);  o = al(o + (size_t)nV * 4);
    float*  sz  = (float*)(ws + o);  o = al(o + (size_t)nV * 4);
    float4* rec = (float4*)(ws + o); o = al(o + (size_t)nF * 48);
    float4* box = (float4*)(ws + o); o = al(o + (size_t)nF * 16);
    (void)ws_size; (void)n_in;      // ~0.95 MB total scratch

    k_prep_verts<<<dim3((nV + 255) / 256), dim3(256), 0, stream>>>(
        verts, Km, Rm, tv, sx, sy, sz, nV);
    k_prep_faces<<<dim3((nF + 255) / 256), dim3(256), 0, stream>>>(
        faces, sx, sy, sz, rec, box, nF);
    dim3 g((W + 7) / 8, (H + 7) / 8);
    k_raster<<<g, dim3(64), 0, stream>>>(
        rec, box, tex, bgc, (float*)d_out, nF, W, H);
}

// Round 2
// 514.085 us; speedup vs baseline: 5.5067x; 5.5067x over previous
//
#include <hip/hip_runtime.h>
#include <math.h>

#define EPSF 1e-8f
#define BIGF 1e30f
#define NSEG 16

// ---------------------------------------------------------------------------
// Kernel 1: project vertices. Bit-exact replica of the numpy f32 op sequence.
// ---------------------------------------------------------------------------
__global__ void k_prep_verts(const float* __restrict__ verts,
                             const float* __restrict__ Km,
                             const float* __restrict__ Rm,
                             const float* __restrict__ tv,
                             float* __restrict__ sx, float* __restrict__ sy,
                             float* __restrict__ sz, int nV)
{
    int v = blockIdx.x * blockDim.x + threadIdx.x;
    if (v >= nV) return;
    float vx = verts[3*v+0], vy = verts[3*v+1], vz = verts[3*v+2];
    float a;
    a = __fadd_rn(__fmul_rn(vx, Rm[0]), __fmul_rn(vy, Rm[1]));
    a = __fadd_rn(a, __fmul_rn(vz, Rm[2]));
    float c0 = __fadd_rn(a, tv[0]);
    a = __fadd_rn(__fmul_rn(vx, Rm[3]), __fmul_rn(vy, Rm[4]));
    a = __fadd_rn(a, __fmul_rn(vz, Rm[5]));
    float c1 = __fadd_rn(a, tv[1]);
    a = __fadd_rn(__fmul_rn(vx, Rm[6]), __fmul_rn(vy, Rm[7]));
    a = __fadd_rn(a, __fmul_rn(vz, Rm[8]));
    float c2 = __fadd_rn(a, tv[2]);

    float u0 = __fadd_rn(__fadd_rn(__fmul_rn(c0, Km[0]), __fmul_rn(c1, Km[1])),
                         __fmul_rn(c2, Km[2]));
    float u1 = __fadd_rn(__fadd_rn(__fmul_rn(c0, Km[3]), __fmul_rn(c1, Km[4])),
                         __fmul_rn(c2, Km[5]));
    sx[v] = __fdiv_rn(u0, c2);
    sy[v] = __fdiv_rn(u1, c2);
    sz[v] = c2;
}

// ---------------------------------------------------------------------------
// Kernel 2: per-face setup (edge coeffs in reference op order, bbox).
// rec[3f+0] = {y12, x21, y20, x02}
// rec[3f+1] = {x2,  y2,  denom, z0}
// rec[3f+2] = {z1,  z2,  0, 0}
// ---------------------------------------------------------------------------
__global__ void k_prep_faces(const int* __restrict__ faces,
                             const float* __restrict__ sx, const float* __restrict__ sy,
                             const float* __restrict__ sz,
                             float4* __restrict__ rec, float4* __restrict__ box, int nF)
{
    int f = blockIdx.x * blockDim.x + threadIdx.x;
    if (f >= nF) return;
    int ia = faces[3*f+0], ib = faces[3*f+1], ic = faces[3*f+2];
    float x0 = sx[ia], y0 = sy[ia], z0 = sz[ia];
    float x1 = sx[ib], y1 = sy[ib], z1 = sz[ib];
    float x2 = sx[ic], y2 = sy[ic], z2 = sz[ic];
    float y12 = __fsub_rn(y1, y2);
    float x21 = __fsub_rn(x2, x1);
    float y20 = __fsub_rn(y2, y0);
    float x02 = __fsub_rn(x0, x2);
    float y02 = __fsub_rn(y0, y2);
    float dn  = __fadd_rn(__fmul_rn(y12, x02), __fmul_rn(x21, y02));
    bool valid = (fabsf(dn) > EPSF) && (fminf(fminf(z0, z1), z2) > EPSF);
    float bxmin, bxmax, bymin, bymax;
    if (valid) {
        bxmin = fminf(fminf(x0, x1), x2) - 0.5f;
        bxmax = fmaxf(fmaxf(x0, x1), x2) + 0.5f;
        bymin = fminf(fminf(y0, y1), y2) - 0.5f;
        bymax = fmaxf(fmaxf(y0, y1), y2) + 0.5f;
    } else {
        bxmin = BIGF; bxmax = -BIGF; bymin = BIGF; bymax = -BIGF;
    }
    rec[3*f+0] = make_float4(y12, x21, y20, x02);
    rec[3*f+1] = make_float4(x2, y2, dn, z0);
    rec[3*f+2] = make_float4(z1, z2, 0.0f, 0.0f);
    box[f]     = make_float4(bxmin, bxmax, bymin, bymax);
}

// ---------------------------------------------------------------------------
// Kernel 3: init packed winner buffer.
// ---------------------------------------------------------------------------
__global__ void k_zinit(unsigned long long* __restrict__ zwin, int P)
{
    int i = blockIdx.x * blockDim.x + threadIdx.x;
    if (i < P) zwin[i] = ~0ull;
}

// ---------------------------------------------------------------------------
// Kernel 4: raster. Grid (tilesX, tilesY, NSEG); one wave per (tile, face-seg).
// Winner merge: atomicMin on (depth_bits<<32 | face_id) — for positive floats
// the uint bit pattern is order-isomorphic, so this is exactly the reference's
// lexicographic (depth, lowest-face-id) rule, and it's commutative ->
// deterministic under graph replay.
// ---------------------------------------------------------------------------
__device__ __forceinline__ void test_face(int f, float4 r0, float4 r1, float4 r2,
                                          float px, float py, float& bd, int& bf)
{
    float dx = __fsub_rn(px, r1.x);
    float dy = __fsub_rn(py, r1.y);
    float n0 = __fadd_rn(__fmul_rn(r0.x, dx), __fmul_rn(r0.y, dy));
    float n1 = __fadd_rn(__fmul_rn(r0.z, dx), __fmul_rn(r0.w, dy));
    float dn = r1.z;
    bool dpos = dn > 0.0f;
    bool in0 = (n0 == 0.0f) || ((n0 > 0.0f) == dpos);  // == (n0/dn >= 0), dn != 0
    bool in1 = (n1 == 0.0f) || ((n1 > 0.0f) == dpos);
    if (in0 && in1) {
        float w0 = __fdiv_rn(n0, dn);
        float w1 = __fdiv_rn(n1, dn);
        float w2 = __fsub_rn(__fsub_rn(1.0f, w0), w1);
        if (w2 >= 0.0f) {
            float a = __fdiv_rn(w0, r1.w);
            float b = __fdiv_rn(w1, r2.x);
            float c = __fdiv_rn(w2, r2.y);
            float iz = __fadd_rn(__fadd_rn(a, b), c);
            if (iz > EPSF) {
                float d = __fdiv_rn(1.0f, iz);
                if ((d < bd) || ((d == bd) && (f < bf))) { bd = d; bf = f; }
            }
        }
    }
}

__global__ __launch_bounds__(64) void k_raster(
    const float4* __restrict__ rec, const float4* __restrict__ box,
    unsigned long long* __restrict__ zwin, int nF, int W, int H)
{
    __shared__ unsigned short list[896];
    int lane = threadIdx.x;
    int tx = lane & 7, ty = lane >> 3;
    int pxi = blockIdx.x * 8 + tx;
    int pyi = blockIdx.y * 8 + ty;
    float px = (float)pxi + 0.5f;
    float py = (float)pyi + 0.5f;
    float rx0 = (float)(blockIdx.x * 8) + 0.5f;
    float rx1 = rx0 + 7.0f;
    float ry0 = (float)(blockIdx.y * 8) + 0.5f;
    float ry1 = ry0 + 7.0f;

    int segsz = (nF + NSEG - 1) / NSEG;
    int beg = blockIdx.z * segsz;
    int end = min(nF, beg + segsz);

    int cnt = 0;
    for (int base = beg; base < end; base += 64) {
        int f = base + lane;
        bool pass = false;
        if (f < end) {
            float4 b = box[f];
            pass = (b.x <= rx1) && (b.y >= rx0) && (b.z <= ry1) && (b.w >= ry0);
        }
        unsigned long long m = __ballot(pass);
        if (pass) {
            int off = __popcll(m & ((1ull << lane) - 1ull));
            list[cnt + off] = (unsigned short)f;
        }
        cnt += (int)__popcll(m);
    }
    __syncthreads();

    float bd = BIGF;
    int bf = 0x7fffffff;
    int i = 0;
    // 4x unrolled: 12 independent scalar loads pipeline across the group.
    for (; i + 4 <= cnt; i += 4) {
        int f0 = __builtin_amdgcn_readfirstlane((int)list[i+0]);
        int f1 = __builtin_amdgcn_readfirstlane((int)list[i+1]);
        int f2 = __builtin_amdgcn_readfirstlane((int)list[i+2]);
        int f3 = __builtin_amdgcn_readfirstlane((int)list[i+3]);
        float4 a0 = rec[3*f0+0], a1 = rec[3*f0+1], a2 = rec[3*f0+2];
        float4 b0 = rec[3*f1+0], b1 = rec[3*f1+1], b2 = rec[3*f1+2];
        float4 c0 = rec[3*f2+0], c1 = rec[3*f2+1], c2 = rec[3*f2+2];
        float4 d0 = rec[3*f3+0], d1 = rec[3*f3+1], d2 = rec[3*f3+2];
        test_face(f0, a0, a1, a2, px, py, bd, bf);
        test_face(f1, b0, b1, b2, px, py, bd, bf);
        test_face(f2, c0, c1, c2, px, py, bd, bf);
        test_face(f3, d0, d1, d2, px, py, bd, bf);
    }
    for (; i < cnt; ++i) {
        int f = __builtin_amdgcn_readfirstlane((int)list[i]);
        float4 a0 = rec[3*f+0], a1 = rec[3*f+1], a2 = rec[3*f+2];
        test_face(f, a0, a1, a2, px, py, bd, bf);
    }

    if (bd < BIGF && pxi < W && pyi < H) {
        unsigned long long pk =
            ((unsigned long long)__float_as_uint(bd) << 32) | (unsigned int)bf;
        atomicMin(&zwin[pyi * W + pxi], pk);
    }
}

// ---------------------------------------------------------------------------
// Kernel 5: shade. One thread per pixel; recompute winner bary (bit-identical
// op sequence) and trilinear-sample its 8^3 texture.
// ---------------------------------------------------------------------------
__global__ void k_shade(const float4* __restrict__ rec,
                        const unsigned long long* __restrict__ zwin,
                        const float* __restrict__ tex, const float* __restrict__ bgc,
                        float* __restrict__ out, int W, int H)
{
    int p = blockIdx.x * blockDim.x + threadIdx.x;
    int P = W * H;
    if (p >= P) return;
    int pxi = p % W, pyi = p / W;
    float px = (float)pxi + 0.5f;
    float py = (float)pyi + 0.5f;

    unsigned long long pk = zwin[p];
    float o0, o1, o2, oa;
    if (pk != ~0ull) {
        int f = (int)(pk & 0xffffffffu);
        float4 r0 = rec[3*f+0];
        float4 r1 = rec[3*f+1];
        float4 r2 = rec[3*f+2];
        float dx = __fsub_rn(px, r1.x);
        float dy = __fsub_rn(py, r1.y);
        float n0 = __fadd_rn(__fmul_rn(r0.x, dx), __fmul_rn(r0.y, dy));
        float n1 = __fadd_rn(__fmul_rn(r0.z, dx), __fmul_rn(r0.w, dy));
        float w0 = __fdiv_rn(n0, r1.z);
        float w1 = __fdiv_rn(n1, r1.z);
        float w2 = __fsub_rn(__fsub_rn(1.0f, w0), w1);
        float c0 = __fdiv_rn(w0, fmaxf(r1.w, EPSF));
        float c1 = __fdiv_rn(w1, fmaxf(r2.x, EPSF));
        float c2 = __fdiv_rn(w2, fmaxf(r2.y, EPSF));
        float s  = __fadd_rn(__fadd_rn(c0, c1), c2);
        s = fmaxf(s, EPSF);
        c0 = __fdiv_rn(c0, s);
        c1 = __fdiv_rn(c1, s);
        c2 = __fdiv_rn(c2, s);
        float p0 = __fmul_rn(fminf(fmaxf(c0, 0.0f), 1.0f), 7.0f);
        float p1 = __fmul_rn(fminf(fmaxf(c1, 0.0f), 1.0f), 7.0f);
        float p2 = __fmul_rn(fminf(fmaxf(c2, 0.0f), 1.0f), 7.0f);
        int i0 = (int)floorf(p0); i0 = i0 < 0 ? 0 : (i0 > 6 ? 6 : i0);
        int i1 = (int)floorf(p1); i1 = i1 < 0 ? 0 : (i1 > 6 ? 6 : i1);
        int i2 = (int)floorf(p2); i2 = i2 < 0 ? 0 : (i2 > 6 ? 6 : i2);
        float f0 = __fsub_rn(p0, (float)i0);
        float f1 = __fsub_rn(p1, (float)i1);
        float f2 = __fsub_rn(p2, (float)i2);
        const float* tb = tex + (size_t)f * (512 * 3);
        float a0 = 0.0f, a1 = 0.0f, a2 = 0.0f;
        #pragma unroll
        for (int d0 = 0; d0 < 2; ++d0) {
            float wx = d0 ? f0 : __fsub_rn(1.0f, f0);
            #pragma unroll
            for (int d1 = 0; d1 < 2; ++d1) {
                float wy = d1 ? f1 : __fsub_rn(1.0f, f1);
                #pragma unroll
                for (int d2 = 0; d2 < 2; ++d2) {
                    float wz = d2 ? f2 : __fsub_rn(1.0f, f2);
                    float w = __fmul_rn(__fmul_rn(wx, wy), wz);
                    int idx = (((i0 + d0) << 6) + ((i1 + d1) << 3) + (i2 + d2)) * 3;
                    a0 = __fadd_rn(a0, __fmul_rn(w, fmaxf(tb[idx + 0], 0.0f)));
                    a1 = __fadd_rn(a1, __fmul_rn(w, fmaxf(tb[idx + 1], 0.0f)));
                    a2 = __fadd_rn(a2, __fmul_rn(w, fmaxf(tb[idx + 2], 0.0f)));
                }
            }
        }
        o0 = a0; o1 = a1; o2 = a2; oa = 1.0f;
    } else {
        o0 = __fdiv_rn(bgc[0], 255.0f);
        o1 = __fdiv_rn(bgc[1], 255.0f);
        o2 = __fdiv_rn(bgc[2], 255.0f);
        oa = 0.0f;
    }
    out[3*p+0] = o0;
    out[3*p+1] = o1;
    out[3*p+2] = o2;
    out[(size_t)P*3 + p] = oa;
}

// ---------------------------------------------------------------------------
extern "C" void kernel_launch(void* const* d_in, const int* in_sizes, int n_in,
                              void* d_out, int out_size, void* d_ws, size_t ws_size,
                              hipStream_t stream)
{
    const float* verts = (const float*)d_in[0];
    const float* Km    = (const float*)d_in[1];
    const float* Rm    = (const float*)d_in[2];
    const float* tv    = (const float*)d_in[3];
    const float* bgc   = (const float*)d_in[4];
    const float* tex   = (const float*)d_in[5];
    const int*   faces = (const int*)d_in[6];
    int nV = in_sizes[0] / 3;
    int nF = in_sizes[6] / 3;
    int P = out_size / 4;                 // rgb(3P) + alpha(P)
    int W = (int)(sqrt((double)P) + 0.5);
    int H = W;

    char* ws = (char*)d_ws;
    size_t o = 0;
    auto al = [](size_t x) { return (x + 255) & ~(size_t)255; };
    float*  sx  = (float*)(ws + o);  o = al(o + (size_t)nV * 4);
    float*  sy  = (float*)(ws + o);  o = al(o + (size_t)nV * 4);
    float*  sz  = (float*)(ws + o);  o = al(o + (size_t)nV * 4);
    float4* rec = (float4*)(ws + o); o = al(o + (size_t)nF * 48);
    float4* box = (float4*)(ws + o); o = al(o + (size_t)nF * 16);
    unsigned long long* zwin = (unsigned long long*)(ws + o);
    o = al(o + (size_t)P * 8);
    (void)ws_size; (void)n_in;           // ~1.5 MB total scratch

    k_prep_verts<<<dim3((nV + 255) / 256), dim3(256), 0, stream>>>(
        verts, Km, Rm, tv, sx, sy, sz, nV);
    k_prep_faces<<<dim3((nF + 255) / 256), dim3(256), 0, stream>>>(
        faces, sx, sy, sz, rec, box, nF);
    k_zinit<<<dim3((P + 255) / 256), dim3(256), 0, stream>>>(zwin, P);
    dim3 g((W + 7) / 8, (H + 7) / 8, NSEG);
    k_raster<<<g, dim3(64), 0, stream>>>(rec, box, zwin, nF, W, H);
    k_shade<<<dim3((P + 255) / 256), dim3(256), 0, stream>>>(
        rec, zwin, tex, bgc, (float*)d_out, W, H);
}

// Round 3
// 296.550 us; speedup vs baseline: 9.5461x; 1.7336x over previous
//
#include <hip/hip_runtime.h>
#include <math.h>

#define EPSF 1e-8f
#define BIGF 1e30f
#define NSEG 64

// ---------------------------------------------------------------------------
// Kernel 1: project vertices. Bit-exact replica of the numpy f32 op sequence.
// ---------------------------------------------------------------------------
__global__ void k_prep_verts(const float* __restrict__ verts,
                             const float* __restrict__ Km,
                             const float* __restrict__ Rm,
                             const float* __restrict__ tv,
                             float* __restrict__ sx, float* __restrict__ sy,
                             float* __restrict__ sz, int nV)
{
    int v = blockIdx.x * blockDim.x + threadIdx.x;
    if (v >= nV) return;
    float vx = verts[3*v+0], vy = verts[3*v+1], vz = verts[3*v+2];
    float a;
    a = __fadd_rn(__fmul_rn(vx, Rm[0]), __fmul_rn(vy, Rm[1]));
    a = __fadd_rn(a, __fmul_rn(vz, Rm[2]));
    float c0 = __fadd_rn(a, tv[0]);
    a = __fadd_rn(__fmul_rn(vx, Rm[3]), __fmul_rn(vy, Rm[4]));
    a = __fadd_rn(a, __fmul_rn(vz, Rm[5]));
    float c1 = __fadd_rn(a, tv[1]);
    a = __fadd_rn(__fmul_rn(vx, Rm[6]), __fmul_rn(vy, Rm[7]));
    a = __fadd_rn(a, __fmul_rn(vz, Rm[8]));
    float c2 = __fadd_rn(a, tv[2]);

    float u0 = __fadd_rn(__fadd_rn(__fmul_rn(c0, Km[0]), __fmul_rn(c1, Km[1])),
                         __fmul_rn(c2, Km[2]));
    float u1 = __fadd_rn(__fadd_rn(__fmul_rn(c0, Km[3]), __fmul_rn(c1, Km[4])),
                         __fmul_rn(c2, Km[5]));
    sx[v] = __fdiv_rn(u0, c2);
    sy[v] = __fdiv_rn(u1, c2);
    sz[v] = c2;
}

// ---------------------------------------------------------------------------
// Kernel 2: per-face setup (edge coeffs in reference op order, bbox).
// rec[3f+0] = {y12, x21, y20, x02}
// rec[3f+1] = {x2,  y2,  denom, z0}
// rec[3f+2] = {z1,  z2,  0, 0}
// ---------------------------------------------------------------------------
__global__ void k_prep_faces(const int* __restrict__ faces,
                             const float* __restrict__ sx, const float* __restrict__ sy,
                             const float* __restrict__ sz,
                             float4* __restrict__ rec, float4* __restrict__ box, int nF)
{
    int f = blockIdx.x * blockDim.x + threadIdx.x;
    if (f >= nF) return;
    int ia = faces[3*f+0], ib = faces[3*f+1], ic = faces[3*f+2];
    float x0 = sx[ia], y0 = sy[ia], z0 = sz[ia];
    float x1 = sx[ib], y1 = sy[ib], z1 = sz[ib];
    float x2 = sx[ic], y2 = sy[ic], z2 = sz[ic];
    float y12 = __fsub_rn(y1, y2);
    float x21 = __fsub_rn(x2, x1);
    float y20 = __fsub_rn(y2, y0);
    float x02 = __fsub_rn(x0, x2);
    float y02 = __fsub_rn(y0, y2);
    float dn  = __fadd_rn(__fmul_rn(y12, x02), __fmul_rn(x21, y02));
    bool valid = (fabsf(dn) > EPSF) && (fminf(fminf(z0, z1), z2) > EPSF);
    float bxmin, bxmax, bymin, bymax;
    if (valid) {
        bxmin = fminf(fminf(x0, x1), x2) - 0.5f;
        bxmax = fmaxf(fmaxf(x0, x1), x2) + 0.5f;
        bymin = fminf(fminf(y0, y1), y2) - 0.5f;
        bymax = fmaxf(fmaxf(y0, y1), y2) + 0.5f;
    } else {
        bxmin = BIGF; bxmax = -BIGF; bymin = BIGF; bymax = -BIGF;
    }
    rec[3*f+0] = make_float4(y12, x21, y20, x02);
    rec[3*f+1] = make_float4(x2, y2, dn, z0);
    rec[3*f+2] = make_float4(z1, z2, 0.0f, 0.0f);
    box[f]     = make_float4(bxmin, bxmax, bymin, bymax);
}

// ---------------------------------------------------------------------------
// Kernel 3: init packed winner buffer.
// ---------------------------------------------------------------------------
__global__ void k_zinit(unsigned long long* __restrict__ zwin, int P)
{
    int i = blockIdx.x * blockDim.x + threadIdx.x;
    if (i < P) zwin[i] = ~0ull;
}

// ---------------------------------------------------------------------------
// Kernel 4: raster. Grid (tilesX/2, tilesY, NSEG); 128-thread block = TWO
// independent waves, each owning one 8x8 tile and one face segment (private
// LDS half, no barrier — single-wave LDS ordering is handled by lgkmcnt).
// Winner merge: atomicMin on (depth_bits<<32 | face_id) — for positive floats
// the uint pattern is order-isomorphic, so this is exactly the reference's
// lexicographic (depth, lowest-face-id) rule; commutative -> deterministic.
// ---------------------------------------------------------------------------
__device__ __forceinline__ void test_face(int f, float4 r0, float4 r1, float4 r2,
                                          float px, float py, float& bd, int& bf)
{
    float dx = __fsub_rn(px, r1.x);
    float dy = __fsub_rn(py, r1.y);
    float n0 = __fadd_rn(__fmul_rn(r0.x, dx), __fmul_rn(r0.y, dy));
    float n1 = __fadd_rn(__fmul_rn(r0.z, dx), __fmul_rn(r0.w, dy));
    float dn = r1.z;
    bool dpos = dn > 0.0f;
    bool in0 = (n0 == 0.0f) || ((n0 > 0.0f) == dpos);  // == (n0/dn >= 0), dn != 0
    bool in1 = (n1 == 0.0f) || ((n1 > 0.0f) == dpos);
    if (in0 && in1) {
        float w0 = __fdiv_rn(n0, dn);
        float w1 = __fdiv_rn(n1, dn);
        float w2 = __fsub_rn(__fsub_rn(1.0f, w0), w1);
        if (w2 >= 0.0f) {
            float a = __fdiv_rn(w0, r1.w);
            float b = __fdiv_rn(w1, r2.x);
            float c = __fdiv_rn(w2, r2.y);
            float iz = __fadd_rn(__fadd_rn(a, b), c);
            if (iz > EPSF) {
                float d = __fdiv_rn(1.0f, iz);
                if ((d < bd) || ((d == bd) && (f < bf))) { bd = d; bf = f; }
            }
        }
    }
}

__global__ __launch_bounds__(128) void k_raster(
    const float4* __restrict__ rec, const float4* __restrict__ box,
    unsigned long long* __restrict__ zwin, int nF, int W, int H)
{
    __shared__ unsigned short list[2][224];   // segsz <= 216
    int wid  = threadIdx.x >> 6;
    int lane = threadIdx.x & 63;
    int tileX = blockIdx.x * 2 + wid;
    int tileY = blockIdx.y;
    int tx = lane & 7, ty = lane >> 3;
    int pxi = tileX * 8 + tx;
    int pyi = tileY * 8 + ty;
    float px = (float)pxi + 0.5f;
    float py = (float)pyi + 0.5f;
    float rx0 = (float)(tileX * 8) + 0.5f;
    float rx1 = rx0 + 7.0f;
    float ry0 = (float)(tileY * 8) + 0.5f;
    float ry1 = ry0 + 7.0f;

    int segsz = (nF + NSEG - 1) / NSEG;
    int beg = blockIdx.z * segsz;
    int end = min(nF, beg + segsz);

    int cnt = 0;
    for (int base = beg; base < end; base += 64) {
        int f = base + lane;
        bool pass = false;
        if (f < end) {
            float4 b = box[f];
            pass = (b.x <= rx1) && (b.y >= rx0) && (b.z <= ry1) && (b.w >= ry0);
        }
        unsigned long long m = __ballot(pass);
        if (pass) {
            int off = __popcll(m & ((1ull << lane) - 1ull));
            list[wid][cnt + off] = (unsigned short)f;
        }
        cnt += (int)__popcll(m);
    }
    // no __syncthreads: each wave reads only its own LDS half; in-wave
    // ds_write->ds_read ordering is enforced by compiler lgkmcnt waits.

    float bd = BIGF;
    int bf = 0x7fffffff;
    int i = 0;
    // 4x unrolled: 12 independent scalar loads pipeline across the group.
    for (; i + 4 <= cnt; i += 4) {
        int f0 = __builtin_amdgcn_readfirstlane((int)list[wid][i+0]);
        int f1 = __builtin_amdgcn_readfirstlane((int)list[wid][i+1]);
        int f2 = __builtin_amdgcn_readfirstlane((int)list[wid][i+2]);
        int f3 = __builtin_amdgcn_readfirstlane((int)list[wid][i+3]);
        float4 a0 = rec[3*f0+0], a1 = rec[3*f0+1], a2 = rec[3*f0+2];
        float4 b0 = rec[3*f1+0], b1 = rec[3*f1+1], b2 = rec[3*f1+2];
        float4 c0 = rec[3*f2+0], c1 = rec[3*f2+1], c2 = rec[3*f2+2];
        float4 d0 = rec[3*f3+0], d1 = rec[3*f3+1], d2 = rec[3*f3+2];
        test_face(f0, a0, a1, a2, px, py, bd, bf);
        test_face(f1, b0, b1, b2, px, py, bd, bf);
        test_face(f2, c0, c1, c2, px, py, bd, bf);
        test_face(f3, d0, d1, d2, px, py, bd, bf);
    }
    for (; i < cnt; ++i) {
        int f = __builtin_amdgcn_readfirstlane((int)list[wid][i]);
        float4 a0 = rec[3*f+0], a1 = rec[3*f+1], a2 = rec[3*f+2];
        test_face(f, a0, a1, a2, px, py, bd, bf);
    }

    if (bd < BIGF && pxi < W && pyi < H) {
        unsigned long long pk =
            ((unsigned long long)__float_as_uint(bd) << 32) | (unsigned int)bf;
        atomicMin(&zwin[pyi * W + pxi], pk);
    }
}

// ---------------------------------------------------------------------------
// Kernel 5: shade. One thread per pixel; recompute winner bary (bit-identical
// op sequence) and trilinear-sample its 8^3 texture.
// ---------------------------------------------------------------------------
__global__ void k_shade(const float4* __restrict__ rec,
                        const unsigned long long* __restrict__ zwin,
                        const float* __restrict__ tex, const float* __restrict__ bgc,
                        float* __restrict__ out, int W, int H)
{
    int p = blockIdx.x * blockDim.x + threadIdx.x;
    int P = W * H;
    if (p >= P) return;
    int pxi = p % W, pyi = p / W;
    float px = (float)pxi + 0.5f;
    float py = (float)pyi + 0.5f;

    unsigned long long pk = zwin[p];
    float o0, o1, o2, oa;
    if (pk != ~0ull) {
        int f = (int)(pk & 0xffffffffu);
        float4 r0 = rec[3*f+0];
        float4 r1 = rec[3*f+1];
        float4 r2 = rec[3*f+2];
        float dx = __fsub_rn(px, r1.x);
        float dy = __fsub_rn(py, r1.y);
        float n0 = __fadd_rn(__fmul_rn(r0.x, dx), __fmul_rn(r0.y, dy));
        float n1 = __fadd_rn(__fmul_rn(r0.z, dx), __fmul_rn(r0.w, dy));
        float w0 = __fdiv_rn(n0, r1.z);
        float w1 = __fdiv_rn(n1, r1.z);
        float w2 = __fsub_rn(__fsub_rn(1.0f, w0), w1);
        float c0 = __fdiv_rn(w0, fmaxf(r1.w, EPSF));
        float c1 = __fdiv_rn(w1, fmaxf(r2.x, EPSF));
        float c2 = __fdiv_rn(w2, fmaxf(r2.y, EPSF));
        float s  = __fadd_rn(__fadd_rn(c0, c1), c2);
        s = fmaxf(s, EPSF);
        c0 = __fdiv_rn(c0, s);
        c1 = __fdiv_rn(c1, s);
        c2 = __fdiv_rn(c2, s);
        float p0 = __fmul_rn(fminf(fmaxf(c0, 0.0f), 1.0f), 7.0f);
        float p1 = __fmul_rn(fminf(fmaxf(c1, 0.0f), 1.0f), 7.0f);
        float p2 = __fmul_rn(fminf(fmaxf(c2, 0.0f), 1.0f), 7.0f);
        int i0 = (int)floorf(p0); i0 = i0 < 0 ? 0 : (i0 > 6 ? 6 : i0);
        int i1 = (int)floorf(p1); i1 = i1 < 0 ? 0 : (i1 > 6 ? 6 : i1);
        int i2 = (int)floorf(p2); i2 = i2 < 0 ? 0 : (i2 > 6 ? 6 : i2);
        float f0 = __fsub_rn(p0, (float)i0);
        float f1 = __fsub_rn(p1, (float)i1);
        float f2 = __fsub_rn(p2, (float)i2);
        const float* tb = tex + (size_t)f * (512 * 3);
        float a0 = 0.0f, a1 = 0.0f, a2 = 0.0f;
        #pragma unroll
        for (int d0 = 0; d0 < 2; ++d0) {
            float wx = d0 ? f0 : __fsub_rn(1.0f, f0);
            #pragma unroll
            for (int d1 = 0; d1 < 2; ++d1) {
                float wy = d1 ? f1 : __fsub_rn(1.0f, f1);
                #pragma unroll
                for (int d2 = 0; d2 < 2; ++d2) {
                    float wz = d2 ? f2 : __fsub_rn(1.0f, f2);
                    float w = __fmul_rn(__fmul_rn(wx, wy), wz);
                    int idx = (((i0 + d0) << 6) + ((i1 + d1) << 3) + (i2 + d2)) * 3;
                    a0 = __fadd_rn(a0, __fmul_rn(w, fmaxf(tb[idx + 0], 0.0f)));
                    a1 = __fadd_rn(a1, __fmul_rn(w, fmaxf(tb[idx + 1], 0.0f)));
                    a2 = __fadd_rn(a2, __fmul_rn(w, fmaxf(tb[idx + 2], 0.0f)));
                }
            }
        }
        o0 = a0; o1 = a1; o2 = a2; oa = 1.0f;
    } else {
        o0 = __fdiv_rn(bgc[0], 255.0f);
        o1 = __fdiv_rn(bgc[1], 255.0f);
        o2 = __fdiv_rn(bgc[2], 255.0f);
        oa = 0.0f;
    }
    out[3*p+0] = o0;
    out[3*p+1] = o1;
    out[3*p+2] = o2;
    out[(size_t)P*3 + p] = oa;
}

// ---------------------------------------------------------------------------
extern "C" void kernel_launch(void* const* d_in, const int* in_sizes, int n_in,
                              void* d_out, int out_size, void* d_ws, size_t ws_size,
                              hipStream_t stream)
{
    const float* verts = (const float*)d_in[0];
    const float* Km    = (const float*)d_in[1];
    const float* Rm    = (const float*)d_in[2];
    const float* tv    = (const float*)d_in[3];
    const float* bgc   = (const float*)d_in[4];
    const float* tex   = (const float*)d_in[5];
    const int*   faces = (const int*)d_in[6];
    int nV = in_sizes[0] / 3;
    int nF = in_sizes[6] / 3;
    int P = out_size / 4;                 // rgb(3P) + alpha(P)
    int W = (int)(sqrt((double)P) + 0.5);
    int H = W;

    char* ws = (char*)d_ws;
    size_t o = 0;
    auto al = [](size_t x) { return (x + 255) & ~(size_t)255; };
    float*  sx  = (float*)(ws + o);  o = al(o + (size_t)nV * 4);
    float*  sy  = (float*)(ws + o);  o = al(o + (size_t)nV * 4);
    float*  sz  = (float*)(ws + o);  o = al(o + (size_t)nV * 4);
    float4* rec = (float4*)(ws + o); o = al(o + (size_t)nF * 48);
    float4* box = (float4*)(ws + o); o = al(o + (size_t)nF * 16);
    unsigned long long* zwin = (unsigned long long*)(ws + o);
    o = al(o + (size_t)P * 8);
    (void)ws_size; (void)n_in;           // ~1.5 MB total scratch

    k_prep_verts<<<dim3((nV + 255) / 256), dim3(256), 0, stream>>>(
        verts, Km, Rm, tv, sx, sy, sz, nV);
    k_prep_faces<<<dim3((nF + 255) / 256), dim3(256), 0, stream>>>(
        faces, sx, sy, sz, rec, box, nF);
    k_zinit<<<dim3((P + 255) / 256), dim3(256), 0, stream>>>(zwin, P);
    int tilesX = (W + 7) / 8, tilesY = (H + 7) / 8;
    dim3 g((tilesX + 1) / 2, tilesY, NSEG);
    k_raster<<<g, dim3(128), 0, stream>>>(rec, box, zwin, nF, W, H);
    k_shade<<<dim3((P + 255) / 256), dim3(256), 0, stream>>>(
        rec, zwin, tex, bgc, (float*)d_out, W, H);
}

// Round 4
// 224.678 us; speedup vs baseline: 12.5997x; 1.3199x over previous
//
#include <hip/hip_runtime.h>
#include <math.h>

#define EPSF 1e-8f
#define BIGF 1e30f
#define NSEG 128
#define SEGSZ 108   // ceil(13776/128); asserted dynamically in launcher

// ---------------------------------------------------------------------------
// Kernel 1: project vertices. Bit-exact replica of the numpy f32 op sequence.
// ---------------------------------------------------------------------------
__global__ void k_prep_verts(const float* __restrict__ verts,
                             const float* __restrict__ Km,
                             const float* __restrict__ Rm,
                             const float* __restrict__ tv,
                             float* __restrict__ sx, float* __restrict__ sy,
                             float* __restrict__ sz, int nV)
{
    int v = blockIdx.x * blockDim.x + threadIdx.x;
    if (v >= nV) return;
    float vx = verts[3*v+0], vy = verts[3*v+1], vz = verts[3*v+2];
    float a;
    a = __fadd_rn(__fmul_rn(vx, Rm[0]), __fmul_rn(vy, Rm[1]));
    a = __fadd_rn(a, __fmul_rn(vz, Rm[2]));
    float c0 = __fadd_rn(a, tv[0]);
    a = __fadd_rn(__fmul_rn(vx, Rm[3]), __fmul_rn(vy, Rm[4]));
    a = __fadd_rn(a, __fmul_rn(vz, Rm[5]));
    float c1 = __fadd_rn(a, tv[1]);
    a = __fadd_rn(__fmul_rn(vx, Rm[6]), __fmul_rn(vy, Rm[7]));
    a = __fadd_rn(a, __fmul_rn(vz, Rm[8]));
    float c2 = __fadd_rn(a, tv[2]);

    float u0 = __fadd_rn(__fadd_rn(__fmul_rn(c0, Km[0]), __fmul_rn(c1, Km[1])),
                         __fmul_rn(c2, Km[2]));
    float u1 = __fadd_rn(__fadd_rn(__fmul_rn(c0, Km[3]), __fmul_rn(c1, Km[4])),
                         __fmul_rn(c2, Km[5]));
    sx[v] = __fdiv_rn(u0, c2);
    sy[v] = __fdiv_rn(u1, c2);
    sz[v] = c2;
}

// ---------------------------------------------------------------------------
// Kernel 2: per-face setup (edge coeffs in reference op order, bbox).
// rec[3f+0] = {y12, x21, y20, x02}
// rec[3f+1] = {x2,  y2,  denom, z0}
// rec[3f+2] = {z1,  z2,  face_id_bits, 0}   (id as raw bits; never FP-touched)
// ---------------------------------------------------------------------------
__global__ void k_prep_faces(const int* __restrict__ faces,
                             const float* __restrict__ sx, const float* __restrict__ sy,
                             const float* __restrict__ sz,
                             float4* __restrict__ rec, float4* __restrict__ box, int nF)
{
    int f = blockIdx.x * blockDim.x + threadIdx.x;
    if (f >= nF) return;
    int ia = faces[3*f+0], ib = faces[3*f+1], ic = faces[3*f+2];
    float x0 = sx[ia], y0 = sy[ia], z0 = sz[ia];
    float x1 = sx[ib], y1 = sy[ib], z1 = sz[ib];
    float x2 = sx[ic], y2 = sy[ic], z2 = sz[ic];
    float y12 = __fsub_rn(y1, y2);
    float x21 = __fsub_rn(x2, x1);
    float y20 = __fsub_rn(y2, y0);
    float x02 = __fsub_rn(x0, x2);
    float y02 = __fsub_rn(y0, y2);
    float dn  = __fadd_rn(__fmul_rn(y12, x02), __fmul_rn(x21, y02));
    bool valid = (fabsf(dn) > EPSF) && (fminf(fminf(z0, z1), z2) > EPSF);
    float bxmin, bxmax, bymin, bymax;
    if (valid) {
        bxmin = fminf(fminf(x0, x1), x2) - 0.5f;
        bxmax = fmaxf(fmaxf(x0, x1), x2) + 0.5f;
        bymin = fminf(fminf(y0, y1), y2) - 0.5f;
        bymax = fmaxf(fmaxf(y0, y1), y2) + 0.5f;
    } else {
        bxmin = BIGF; bxmax = -BIGF; bymin = BIGF; bymax = -BIGF;
    }
    rec[3*f+0] = make_float4(y12, x21, y20, x02);
    rec[3*f+1] = make_float4(x2, y2, dn, z0);
    rec[3*f+2] = make_float4(z1, z2, __int_as_float(f), 0.0f);
    box[f]     = make_float4(bxmin, bxmax, bymin, bymax);
}

// ---------------------------------------------------------------------------
// Kernel 3: init packed winner buffer.
// ---------------------------------------------------------------------------
__global__ void k_zinit(unsigned long long* __restrict__ zwin, int P)
{
    int i = blockIdx.x * blockDim.x + threadIdx.x;
    if (i < P) zwin[i] = ~0ull;
}

// ---------------------------------------------------------------------------
// Kernel 4: raster. Block = 256 thr = 4 independent waves; wave w handles
// tile (blockIdx.x*4+w) and face segment blockIdx.y, staging surviving face
// records into its private LDS quarter, then branchless z-testing them.
// Winner merge: atomicMin on (depth_bits<<32 | face_id) — exact reference
// lexicographic (depth, lowest-id) rule; commutative -> deterministic.
// ---------------------------------------------------------------------------
__device__ __forceinline__ void test_face_bl(float4 r0, float4 r1, float4 r2,
                                             float px, float py,
                                             float& bd, int& bf)
{
    float dx = __fsub_rn(px, r1.x);
    float dy = __fsub_rn(py, r1.y);
    float n0 = __fadd_rn(__fmul_rn(r0.x, dx), __fmul_rn(r0.y, dy));
    float n1 = __fadd_rn(__fmul_rn(r0.z, dx), __fmul_rn(r0.w, dy));
    float dn = r1.z;                       // |dn| > EPS guaranteed (staged only)
    bool dpos = dn > 0.0f;
    bool in0 = (n0 == 0.0f) || ((n0 > 0.0f) == dpos);   // == (n0/dn >= 0)
    bool in1 = (n1 == 0.0f) || ((n1 > 0.0f) == dpos);
    float w0 = __fdiv_rn(n0, dn);
    float w1 = __fdiv_rn(n1, dn);
    float w2 = __fsub_rn(__fsub_rn(1.0f, w0), w1);
    float a  = __fdiv_rn(w0, r1.w);
    float b  = __fdiv_rn(w1, r2.x);
    float c  = __fdiv_rn(w2, r2.y);
    float iz = __fadd_rn(__fadd_rn(a, b), c);
    float d  = __fdiv_rn(1.0f, iz);
    int   f  = __float_as_int(r2.z);
    bool ok = in0 && in1 && (w2 >= 0.0f) && (iz > EPSF);
    bool better = ok && ((d < bd) || ((d == bd) && (f < bf)));
    bd = better ? d : bd;
    bf = better ? f : bf;
}

__global__ __launch_bounds__(256) void k_raster(
    const float4* __restrict__ rec, const float4* __restrict__ box,
    unsigned long long* __restrict__ zwin, int nF, int W, int H)
{
    __shared__ float4 slds[4][SEGSZ * 3];   // 4 x 5184 B = 20736 B
    int wid  = threadIdx.x >> 6;
    int lane = threadIdx.x & 63;
    int tile = blockIdx.x * 4 + wid;
    int tileX = tile & 31, tileY = tile >> 5;
    int tx = lane & 7, ty = lane >> 3;
    int pxi = tileX * 8 + tx;
    int pyi = tileY * 8 + ty;
    float px = (float)pxi + 0.5f;
    float py = (float)pyi + 0.5f;
    float rx0 = (float)(tileX * 8) + 0.5f;
    float rx1 = rx0 + 7.0f;
    float ry0 = (float)(tileY * 8) + 0.5f;
    float ry1 = ry0 + 7.0f;
    float cx  = (float)(tileX * 8) + 4.0f;   // pixel centers span cx +/- 3.5
    float cy  = (float)(tileY * 8) + 4.0f;

    int beg = blockIdx.y * SEGSZ;
    int end = min(nF, beg + SEGSZ);

    // ---- Phase A: cull (bbox + conservative edge-vs-tile) and stage to LDS.
    float4* my = slds[wid];
    int cnt = 0;
    for (int base = beg; base < end; base += 64) {
        int f = base + lane;
        bool pass = false;
        float4 r0, r1, r2;
        if (f < end) {
            float4 b = box[f];
            pass = (b.x <= rx1) && (b.y >= rx0) && (b.z <= ry1) && (b.w >= ry0);
        }
        if (pass) {
            r0 = rec[3*f+0]; r1 = rec[3*f+1]; r2 = rec[3*f+2];
            // Conservative reject: max of s*edge over pixel centers < 0 ->
            // no pixel can be inside. 3.6 > 3.5 margin swamps fp error;
            // perf-only filter, plain fp math is fine.
            float s  = (r1.z > 0.0f) ? 1.0f : -1.0f;
            float dx = cx - r1.x, dy = cy - r1.y;
            float n0c = r0.x * dx + r0.y * dy;
            float n1c = r0.z * dx + r0.w * dy;
            float t0 = s * n0c + 3.6f * (fabsf(r0.x) + fabsf(r0.y));
            float t1 = s * n1c + 3.6f * (fabsf(r0.z) + fabsf(r0.w));
            float t2 = s * (r1.z - n0c - n1c)
                     + 3.6f * (fabsf(r0.x + r0.z) + fabsf(r0.y + r0.w));
            pass = (t0 >= 0.0f) && (t1 >= 0.0f) && (t2 >= 0.0f);
        }
        unsigned long long m = __ballot(pass);
        if (pass) {
            int slot = cnt + __popcll(m & ((1ull << lane) - 1ull));
            my[slot*3+0] = r0;
            my[slot*3+1] = r1;
            my[slot*3+2] = r2;
        }
        cnt += (int)__popcll(m);
    }
    // no __syncthreads: each wave reads only its own LDS quarter; in-wave
    // ds ordering is enforced by compiler lgkmcnt waits.

    // ---- Phase B: branchless z-test, 4x unrolled independent chains.
    float bd = BIGF;
    int bf = 0x7fffffff;
    int i = 0;
    for (; i + 4 <= cnt; i += 4) {
        float4 a0 = my[(i+0)*3+0], a1 = my[(i+0)*3+1], a2 = my[(i+0)*3+2];
        float4 b0 = my[(i+1)*3+0], b1 = my[(i+1)*3+1], b2 = my[(i+1)*3+2];
        float4 c0 = my[(i+2)*3+0], c1 = my[(i+2)*3+1], c2 = my[(i+2)*3+2];
        float4 d0 = my[(i+3)*3+0], d1 = my[(i+3)*3+1], d2 = my[(i+3)*3+2];
        test_face_bl(a0, a1, a2, px, py, bd, bf);
        test_face_bl(b0, b1, b2, px, py, bd, bf);
        test_face_bl(c0, c1, c2, px, py, bd, bf);
        test_face_bl(d0, d1, d2, px, py, bd, bf);
    }
    for (; i < cnt; ++i) {
        float4 a0 = my[i*3+0], a1 = my[i*3+1], a2 = my[i*3+2];
        test_face_bl(a0, a1, a2, px, py, bd, bf);
    }

    if (bd < BIGF && pxi < W && pyi < H) {
        unsigned long long pk =
            ((unsigned long long)__float_as_uint(bd) << 32) | (unsigned int)bf;
        atomicMin(&zwin[pyi * W + pxi], pk);
    }
}

// ---------------------------------------------------------------------------
// Kernel 5: shade. One thread per pixel; recompute winner bary (bit-identical
// op sequence) and trilinear-sample its 8^3 texture.
// ---------------------------------------------------------------------------
__global__ void k_shade(const float4* __restrict__ rec,
                        const unsigned long long* __restrict__ zwin,
                        const float* __restrict__ tex, const float* __restrict__ bgc,
                        float* __restrict__ out, int W, int H)
{
    int p = blockIdx.x * blockDim.x + threadIdx.x;
    int P = W * H;
    if (p >= P) return;
    int pxi = p % W, pyi = p / W;
    float px = (float)pxi + 0.5f;
    float py = (float)pyi + 0.5f;

    unsigned long long pk = zwin[p];
    float o0, o1, o2, oa;
    if (pk != ~0ull) {
        int f = (int)(pk & 0xffffffffu);
        float4 r0 = rec[3*f+0];
        float4 r1 = rec[3*f+1];
        float4 r2 = rec[3*f+2];
        float dx = __fsub_rn(px, r1.x);
        float dy = __fsub_rn(py, r1.y);
        float n0 = __fadd_rn(__fmul_rn(r0.x, dx), __fmul_rn(r0.y, dy));
        float n1 = __fadd_rn(__fmul_rn(r0.z, dx), __fmul_rn(r0.w, dy));
        float w0 = __fdiv_rn(n0, r1.z);
        float w1 = __fdiv_rn(n1, r1.z);
        float w2 = __fsub_rn(__fsub_rn(1.0f, w0), w1);
        float c0 = __fdiv_rn(w0, fmaxf(r1.w, EPSF));
        float c1 = __fdiv_rn(w1, fmaxf(r2.x, EPSF));
        float c2 = __fdiv_rn(w2, fmaxf(r2.y, EPSF));
        float s  = __fadd_rn(__fadd_rn(c0, c1), c2);
        s = fmaxf(s, EPSF);
        c0 = __fdiv_rn(c0, s);
        c1 = __fdiv_rn(c1, s);
        c2 = __fdiv_rn(c2, s);
        float p0 = __fmul_rn(fminf(fmaxf(c0, 0.0f), 1.0f), 7.0f);
        float p1 = __fmul_rn(fminf(fmaxf(c1, 0.0f), 1.0f), 7.0f);
        float p2 = __fmul_rn(fminf(fmaxf(c2, 0.0f), 1.0f), 7.0f);
        int i0 = (int)floorf(p0); i0 = i0 < 0 ? 0 : (i0 > 6 ? 6 : i0);
        int i1 = (int)floorf(p1); i1 = i1 < 0 ? 0 : (i1 > 6 ? 6 : i1);
        int i2 = (int)floorf(p2); i2 = i2 < 0 ? 0 : (i2 > 6 ? 6 : i2);
        float f0 = __fsub_rn(p0, (float)i0);
        float f1 = __fsub_rn(p1, (float)i1);
        float f2 = __fsub_rn(p2, (float)i2);
        const float* tb = tex + (size_t)f * (512 * 3);
        float a0 = 0.0f, a1 = 0.0f, a2 = 0.0f;
        #pragma unroll
        for (int d0 = 0; d0 < 2; ++d0) {
            float wx = d0 ? f0 : __fsub_rn(1.0f, f0);
            #pragma unroll
            for (int d1 = 0; d1 < 2; ++d1) {
                float wy = d1 ? f1 : __fsub_rn(1.0f, f1);
                #pragma unroll
                for (int d2 = 0; d2 < 2; ++d2) {
                    float wz = d2 ? f2 : __fsub_rn(1.0f, f2);
                    float w = __fmul_rn(__fmul_rn(wx, wy), wz);
                    int idx = (((i0 + d0) << 6) + ((i1 + d1) << 3) + (i2 + d2)) * 3;
                    a0 = __fadd_rn(a0, __fmul_rn(w, fmaxf(tb[idx + 0], 0.0f)));
                    a1 = __fadd_rn(a1, __fmul_rn(w, fmaxf(tb[idx + 1], 0.0f)));
                    a2 = __fadd_rn(a2, __fmul_rn(w, fmaxf(tb[idx + 2], 0.0f)));
                }
            }
        }
        o0 = a0; o1 = a1; o2 = a2; oa = 1.0f;
    } else {
        o0 = __fdiv_rn(bgc[0], 255.0f);
        o1 = __fdiv_rn(bgc[1], 255.0f);
        o2 = __fdiv_rn(bgc[2], 255.0f);
        oa = 0.0f;
    }
    out[3*p+0] = o0;
    out[3*p+1] = o1;
    out[3*p+2] = o2;
    out[(size_t)P*3 + p] = oa;
}

// ---------------------------------------------------------------------------
extern "C" void kernel_launch(void* const* d_in, const int* in_sizes, int n_in,
                              void* d_out, int out_size, void* d_ws, size_t ws_size,
                              hipStream_t stream)
{
    const float* verts = (const float*)d_in[0];
    const float* Km    = (const float*)d_in[1];
    const float* Rm    = (const float*)d_in[2];
    const float* tv    = (const float*)d_in[3];
    const float* bgc   = (const float*)d_in[4];
    const float* tex   = (const float*)d_in[5];
    const int*   faces = (const int*)d_in[6];
    int nV = in_sizes[0] / 3;
    int nF = in_sizes[6] / 3;
    int P = out_size / 4;                 // rgb(3P) + alpha(P)
    int W = (int)(sqrt((double)P) + 0.5);
    int H = W;

    char* ws = (char*)d_ws;
    size_t o = 0;
    auto al = [](size_t x) { return (x + 255) & ~(size_t)255; };
    float*  sx  = (float*)(ws + o);  o = al(o + (size_t)nV * 4);
    float*  sy  = (float*)(ws + o);  o = al(o + (size_t)nV * 4);
    float*  sz  = (float*)(ws + o);  o = al(o + (size_t)nV * 4);
    float4* rec = (float4*)(ws + o); o = al(o + (size_t)nF * 48);
    float4* box = (float4*)(ws + o); o = al(o + (size_t)nF * 16);
    unsigned long long* zwin = (unsigned long long*)(ws + o);
    o = al(o + (size_t)P * 8);
    (void)ws_size; (void)n_in;           // ~1.5 MB total scratch

    k_prep_verts<<<dim3((nV + 255) / 256), dim3(256), 0, stream>>>(
        verts, Km, Rm, tv, sx, sy, sz, nV);
    k_prep_faces<<<dim3((nF + 255) / 256), dim3(256), 0, stream>>>(
        faces, sx, sy, sz, rec, box, nF);
    k_zinit<<<dim3((P + 255) / 256), dim3(256), 0, stream>>>(zwin, P);

    int tilesX = (W + 7) / 8, tilesY = (H + 7) / 8;
    int nTiles = tilesX * tilesY;
    // k_raster assumes 32x32 tiles (tile&31 indexing) and SEGSZ*NSEG >= nF.
    // Both hold for the benched shape (W=H=256, nF=13776); guard anyway.
    if (tilesX == 32 && tilesY == 32 && nF <= NSEG * SEGSZ) {
        dim3 g(nTiles / 4, NSEG, 1);
        k_raster<<<g, dim3(256), 0, stream>>>(rec, box, zwin, nF, W, H);
    } else {
        dim3 g(nTiles / 4, (nF + SEGSZ - 1) / SEGSZ, 1);
        k_raster<<<g, dim3(256), 0, stream>>>(rec, box, zwin, nF, W, H);
    }
    k_shade<<<dim3((P + 255) / 256), dim3(256), 0, stream>>>(
        rec, zwin, tex, bgc, (float*)d_out, W, H);
}

// Round 5
// 76.242 us; speedup vs baseline: 37.1301x; 2.9469x over previous
//
#include <hip/hip_runtime.h>
#include <math.h>

#define EPSF 1e-8f
#define BIGF 1e30f
#define SEGSZ 216   // faces per segment; grid.y = ceil(nF/SEGSZ)

__device__ __forceinline__ float fastrcp(float x) {
    float y;
    asm("v_rcp_f32 %0, %1" : "=v"(y) : "v"(x));   // ~1 ulp; perf-filter only
    return y;
}

// ---------------------------------------------------------------------------
// Kernel 1: project vertices. Bit-exact replica of the numpy f32 op sequence.
// ---------------------------------------------------------------------------
__global__ void k_prep_verts(const float* __restrict__ verts,
                             const float* __restrict__ Km,
                             const float* __restrict__ Rm,
                             const float* __restrict__ tv,
                             float* __restrict__ sx, float* __restrict__ sy,
                             float* __restrict__ sz, int nV)
{
    int v = blockIdx.x * blockDim.x + threadIdx.x;
    if (v >= nV) return;
    float vx = verts[3*v+0], vy = verts[3*v+1], vz = verts[3*v+2];
    float a;
    a = __fadd_rn(__fmul_rn(vx, Rm[0]), __fmul_rn(vy, Rm[1]));
    a = __fadd_rn(a, __fmul_rn(vz, Rm[2]));
    float c0 = __fadd_rn(a, tv[0]);
    a = __fadd_rn(__fmul_rn(vx, Rm[3]), __fmul_rn(vy, Rm[4]));
    a = __fadd_rn(a, __fmul_rn(vz, Rm[5]));
    float c1 = __fadd_rn(a, tv[1]);
    a = __fadd_rn(__fmul_rn(vx, Rm[6]), __fmul_rn(vy, Rm[7]));
    a = __fadd_rn(a, __fmul_rn(vz, Rm[8]));
    float c2 = __fadd_rn(a, tv[2]);

    float u0 = __fadd_rn(__fadd_rn(__fmul_rn(c0, Km[0]), __fmul_rn(c1, Km[1])),
                         __fmul_rn(c2, Km[2]));
    float u1 = __fadd_rn(__fadd_rn(__fmul_rn(c0, Km[3]), __fmul_rn(c1, Km[4])),
                         __fmul_rn(c2, Km[5]));
    sx[v] = __fdiv_rn(u0, c2);
    sy[v] = __fdiv_rn(u1, c2);
    sz[v] = c2;
}

// ---------------------------------------------------------------------------
// Kernel 2: per-face setup (edge coeffs in reference op order, bbox).
// rec[3f+0] = {y12, x21, y20, x02}
// rec[3f+1] = {x2,  y2,  denom, z0}
// rec[3f+2] = {z1,  z2,  face_id_bits, 0}
// ---------------------------------------------------------------------------
__global__ void k_prep_faces(const int* __restrict__ faces,
                             const float* __restrict__ sx, const float* __restrict__ sy,
                             const float* __restrict__ sz,
                             float4* __restrict__ rec, float4* __restrict__ box, int nF)
{
    int f = blockIdx.x * blockDim.x + threadIdx.x;
    if (f >= nF) return;
    int ia = faces[3*f+0], ib = faces[3*f+1], ic = faces[3*f+2];
    float x0 = sx[ia], y0 = sy[ia], z0 = sz[ia];
    float x1 = sx[ib], y1 = sy[ib], z1 = sz[ib];
    float x2 = sx[ic], y2 = sy[ic], z2 = sz[ic];
    float y12 = __fsub_rn(y1, y2);
    float x21 = __fsub_rn(x2, x1);
    float y20 = __fsub_rn(y2, y0);
    float x02 = __fsub_rn(x0, x2);
    float y02 = __fsub_rn(y0, y2);
    float dn  = __fadd_rn(__fmul_rn(y12, x02), __fmul_rn(x21, y02));
    bool valid = (fabsf(dn) > EPSF) && (fminf(fminf(z0, z1), z2) > EPSF);
    float bxmin, bxmax, bymin, bymax;
    if (valid) {
        bxmin = fminf(fminf(x0, x1), x2) - 0.5f;
        bxmax = fmaxf(fmaxf(x0, x1), x2) + 0.5f;
        bymin = fminf(fminf(y0, y1), y2) - 0.5f;
        bymax = fmaxf(fmaxf(y0, y1), y2) + 0.5f;
    } else {
        bxmin = BIGF; bxmax = -BIGF; bymin = BIGF; bymax = -BIGF;
    }
    rec[3*f+0] = make_float4(y12, x21, y20, x02);
    rec[3*f+1] = make_float4(x2, y2, dn, z0);
    rec[3*f+2] = make_float4(z1, z2, __int_as_float(f), 0.0f);
    box[f]     = make_float4(bxmin, bxmax, bymin, bymax);
}

// ---------------------------------------------------------------------------
// Kernel 3: init packed winner buffer to (BIGF, id=0x7fffffff).
// ---------------------------------------------------------------------------
__global__ void k_zinit(unsigned long long* __restrict__ zwin, int P)
{
    int i = blockIdx.x * blockDim.x + threadIdx.x;
    unsigned long long initpk =
        ((unsigned long long)__float_as_uint(BIGF) << 32) | 0x7fffffffu;
    if (i < P) zwin[i] = initpk;
}

// ---------------------------------------------------------------------------
// Kernel 4: raster. 256 thr = 4 independent waves; wave = (tile, segment).
// Per-pixel best seeded from zwin (monotone-min => race-safe, deterministic);
// approximate rcp-based prefilters skip the exact 7-divide path for faces
// provably worse than the seeded best (margins >> rcp error); exact path is
// op-for-op the reference sequence. atomicMin on (depth_bits<<32|id) packs
// the reference's lexicographic (depth, lowest-id) winner rule.
// ---------------------------------------------------------------------------
__global__ __launch_bounds__(256) void k_raster(
    const float4* __restrict__ rec, const float4* __restrict__ box,
    unsigned long long* __restrict__ zwin, int nF, int W, int H,
    int tilesX, int nTiles)
{
    __shared__ float4 slds[4][64 * 3];   // 12288 B
    int wid  = threadIdx.x >> 6;
    int lane = threadIdx.x & 63;
    int tile = blockIdx.x * 4 + wid;
    if (tile >= nTiles) return;
    int tileX = tile % tilesX, tileY = tile / tilesX;
    int tx = lane & 7, ty = lane >> 3;
    int pxi = tileX * 8 + tx;
    int pyi = tileY * 8 + ty;
    float px = (float)pxi + 0.5f;
    float py = (float)pyi + 0.5f;
    float rx0 = (float)(tileX * 8) + 0.5f;
    float rx1 = rx0 + 7.0f;
    float ry0 = (float)(tileY * 8) + 0.5f;
    float ry1 = ry0 + 7.0f;
    float cx  = (float)(tileX * 8) + 4.0f;
    float cy  = (float)(tileY * 8) + 4.0f;

    int beg = blockIdx.y * SEGSZ;
    int end = min(nF, beg + SEGSZ);
    if (beg >= end) return;

    int pidx = pyi * W + pxi;
    unsigned long long seed = zwin[pidx];      // stale reads are sound
    float bd = __uint_as_float((unsigned)(seed >> 32));
    int   bf = (int)(unsigned)(seed & 0xffffffffu);

    float4* my = slds[wid];

    // -- software pipeline: loads for chunk k+1 fly during finish+drain of k.
    float4 pb, p0, p1, p2;
    {
        int f = beg + lane;
        int fc = (f < end) ? f : (end - 1);
        pb = box[fc];
        p0 = rec[3*fc+0]; p1 = rec[3*fc+1]; p2 = rec[3*fc+2];
    }

    for (int base = beg; base < end; base += 64) {
        float4 cb = pb, c0 = p0, c1 = p1, c2 = p2;
        if (base + 64 < end) {
            int f = base + 64 + lane;
            int fc = (f < end) ? f : (end - 1);
            pb = box[fc];
            p0 = rec[3*fc+0]; p1 = rec[3*fc+1]; p2 = rec[3*fc+2];
        }
        int f = base + lane;
        bool pass = (f < end) &&
                    (cb.x <= rx1) && (cb.y >= rx0) && (cb.z <= ry1) && (cb.w >= ry0);
        if (pass) {
            // conservative edge-vs-tile reject (3.6 > 3.5 px margin, perf-only)
            float s  = (c1.z > 0.0f) ? 1.0f : -1.0f;
            float dx = cx - c1.x, dy = cy - c1.y;
            float n0c = c0.x * dx + c0.y * dy;
            float n1c = c0.z * dx + c0.w * dy;
            float t0 = s * n0c + 3.6f * (fabsf(c0.x) + fabsf(c0.y));
            float t1 = s * n1c + 3.6f * (fabsf(c0.z) + fabsf(c0.w));
            float t2 = s * (c1.z - n0c - n1c)
                     + 3.6f * (fabsf(c0.x + c0.z) + fabsf(c0.y + c0.w));
            pass = (t0 >= 0.0f) && (t1 >= 0.0f) && (t2 >= 0.0f);
        }
        unsigned long long m = __ballot(pass);
        if (pass) {
            int slot = __popcll(m & ((1ull << lane) - 1ull));
            my[slot*3+0] = c0; my[slot*3+1] = c1; my[slot*3+2] = c2;
        }
        int cnt = (int)__popcll(m);

        for (int j = 0; j < cnt; ++j) {
            float4 r0 = my[j*3+0], r1 = my[j*3+1], r2 = my[j*3+2];
            // face-level skip: depth >= zmin*(1-4e-7); margin 1e-3 is sound
            float zmin = fminf(fminf(r1.w, r2.x), r2.y);
            if (!__any(zmin <= __fmul_rn(bd, 1.001f))) continue;

            float dx = __fsub_rn(px, r1.x);
            float dy = __fsub_rn(py, r1.y);
            float n0 = __fadd_rn(__fmul_rn(r0.x, dx), __fmul_rn(r0.y, dy));
            float n1 = __fadd_rn(__fmul_rn(r0.z, dx), __fmul_rn(r0.w, dy));
            float dn = r1.z;
            bool dpos = dn > 0.0f;
            bool in0 = (n0 == 0.0f) || ((n0 > 0.0f) == dpos);  // == (n0/dn >= 0)
            bool in1 = (n1 == 0.0f) || ((n1 > 0.0f) == dpos);
            bool cand = in0 && in1;
            if (cand) {
                float rdn = fastrcp(dn);
                float w0a = n0 * rdn, w1a = n1 * rdn;
                float w2a = 1.0f - w0a - w1a;
                float ss  = 1.0f + fabsf(w0a) + fabsf(w1a);
                cand = (w2a >= -1e-4f * ss);       // err(w2a) <= 3e-7*ss
                if (cand) {
                    // near-inside: w0a,w1a>=0, w0a+w1a<=~1.0002, z>0 -> iza>0
                    float iza = w0a * fastrcp(r1.w) + w1a * fastrcp(r2.x)
                              + w2a * fastrcp(r2.y);
                    float da  = fastrcp(iza);
                    cand = (da <= __fmul_rn(bd, 1.001f));  // err(da) <= ~1.5e-4
                }
            }
            if (cand) {   // exact path: byte-identical reference op sequence
                float w0 = __fdiv_rn(n0, dn);
                float w1 = __fdiv_rn(n1, dn);
                float w2 = __fsub_rn(__fsub_rn(1.0f, w0), w1);
                if (w2 >= 0.0f) {
                    float a  = __fdiv_rn(w0, r1.w);
                    float b2 = __fdiv_rn(w1, r2.x);
                    float c  = __fdiv_rn(w2, r2.y);
                    float iz = __fadd_rn(__fadd_rn(a, b2), c);
                    if (iz > EPSF) {
                        float d = __fdiv_rn(1.0f, iz);
                        int  fc = __float_as_int(r2.z);
                        if ((d < bd) || ((d == bd) && (fc < bf))) { bd = d; bf = fc; }
                    }
                }
            }
        }
    }

    unsigned long long pk =
        ((unsigned long long)__float_as_uint(bd) << 32) | (unsigned int)bf;
    if (pk < seed) atomicMin(&zwin[pidx], pk);
}

// ---------------------------------------------------------------------------
// Kernel 5: shade. One thread per pixel; recompute winner bary (bit-identical
// op sequence) and trilinear-sample its 8^3 texture.
// ---------------------------------------------------------------------------
__global__ void k_shade(const float4* __restrict__ rec,
                        const unsigned long long* __restrict__ zwin,
                        const float* __restrict__ tex, const float* __restrict__ bgc,
                        float* __restrict__ out, int W, int H)
{
    int p = blockIdx.x * blockDim.x + threadIdx.x;
    int P = W * H;
    if (p >= P) return;
    int pxi = p % W, pyi = p / W;
    float px = (float)pxi + 0.5f;
    float py = (float)pyi + 0.5f;

    unsigned long long pk = zwin[p];
    float o0, o1, o2, oa;
    if ((unsigned)(pk >> 32) != __float_as_uint(BIGF)) {
        int f = (int)(pk & 0xffffffffu);
        float4 r0 = rec[3*f+0];
        float4 r1 = rec[3*f+1];
        float4 r2 = rec[3*f+2];
        float dx = __fsub_rn(px, r1.x);
        float dy = __fsub_rn(py, r1.y);
        float n0 = __fadd_rn(__fmul_rn(r0.x, dx), __fmul_rn(r0.y, dy));
        float n1 = __fadd_rn(__fmul_rn(r0.z, dx), __fmul_rn(r0.w, dy));
        float w0 = __fdiv_rn(n0, r1.z);
        float w1 = __fdiv_rn(n1, r1.z);
        float w2 = __fsub_rn(__fsub_rn(1.0f, w0), w1);
        float c0 = __fdiv_rn(w0, fmaxf(r1.w, EPSF));
        float c1 = __fdiv_rn(w1, fmaxf(r2.x, EPSF));
        float c2 = __fdiv_rn(w2, fmaxf(r2.y, EPSF));
        float s  = __fadd_rn(__fadd_rn(c0, c1), c2);
        s = fmaxf(s, EPSF);
        c0 = __fdiv_rn(c0, s);
        c1 = __fdiv_rn(c1, s);
        c2 = __fdiv_rn(c2, s);
        float p0 = __fmul_rn(fminf(fmaxf(c0, 0.0f), 1.0f), 7.0f);
        float p1 = __fmul_rn(fminf(fmaxf(c1, 0.0f), 1.0f), 7.0f);
        float p2 = __fmul_rn(fminf(fmaxf(c2, 0.0f), 1.0f), 7.0f);
        int i0 = (int)floorf(p0); i0 = i0 < 0 ? 0 : (i0 > 6 ? 6 : i0);
        int i1 = (int)floorf(p1); i1 = i1 < 0 ? 0 : (i1 > 6 ? 6 : i1);
        int i2 = (int)floorf(p2); i2 = i2 < 0 ? 0 : (i2 > 6 ? 6 : i2);
        float f0 = __fsub_rn(p0, (float)i0);
        float f1 = __fsub_rn(p1, (float)i1);
        float f2 = __fsub_rn(p2, (float)i2);
        const float* tb = tex + (size_t)f * (512 * 3);
        float a0 = 0.0f, a1 = 0.0f, a2 = 0.0f;
        #pragma unroll
        for (int d0 = 0; d0 < 2; ++d0) {
            float wx = d0 ? f0 : __fsub_rn(1.0f, f0);
            #pragma unroll
            for (int d1 = 0; d1 < 2; ++d1) {
                float wy = d1 ? f1 : __fsub_rn(1.0f, f1);
                #pragma unroll
                for (int d2 = 0; d2 < 2; ++d2) {
                    float wz = d2 ? f2 : __fsub_rn(1.0f, f2);
                    float w = __fmul_rn(__fmul_rn(wx, wy), wz);
                    int idx = (((i0 + d0) << 6) + ((i1 + d1) << 3) + (i2 + d2)) * 3;
                    a0 = __fadd_rn(a0, __fmul_rn(w, fmaxf(tb[idx + 0], 0.0f)));
                    a1 = __fadd_rn(a1, __fmul_rn(w, fmaxf(tb[idx + 1], 0.0f)));
                    a2 = __fadd_rn(a2, __fmul_rn(w, fmaxf(tb[idx + 2], 0.0f)));
                }
            }
        }
        o0 = a0; o1 = a1; o2 = a2; oa = 1.0f;
    } else {
        o0 = __fdiv_rn(bgc[0], 255.0f);
        o1 = __fdiv_rn(bgc[1], 255.0f);
        o2 = __fdiv_rn(bgc[2], 255.0f);
        oa = 0.0f;
    }
    out[3*p+0] = o0;
    out[3*p+1] = o1;
    out[3*p+2] = o2;
    out[(size_t)P*3 + p] = oa;
}

// ---------------------------------------------------------------------------
extern "C" void kernel_launch(void* const* d_in, const int* in_sizes, int n_in,
                              void* d_out, int out_size, void* d_ws, size_t ws_size,
                              hipStream_t stream)
{
    const float* verts = (const float*)d_in[0];
    const float* Km    = (const float*)d_in[1];
    const float* Rm    = (const float*)d_in[2];
    const float* tv    = (const float*)d_in[3];
    const float* bgc   = (const float*)d_in[4];
    const float* tex   = (const float*)d_in[5];
    const int*   faces = (const int*)d_in[6];
    int nV = in_sizes[0] / 3;
    int nF = in_sizes[6] / 3;
    int P = out_size / 4;                 // rgb(3P) + alpha(P)
    int W = (int)(sqrt((double)P) + 0.5);
    int H = W;

    char* ws = (char*)d_ws;
    size_t o = 0;
    auto al = [](size_t x) { return (x + 255) & ~(size_t)255; };
    float*  sx  = (float*)(ws + o);  o = al(o + (size_t)nV * 4);
    float*  sy  = (float*)(ws + o);  o = al(o + (size_t)nV * 4);
    float*  sz  = (float*)(ws + o);  o = al(o + (size_t)nV * 4);
    float4* rec = (float4*)(ws + o); o = al(o + (size_t)nF * 48);
    float4* box = (float4*)(ws + o); o = al(o + (size_t)nF * 16);
    unsigned long long* zwin = (unsigned long long*)(ws + o);
    o = al(o + (size_t)P * 8);
    (void)ws_size; (void)n_in;           // ~1.5 MB total scratch

    k_prep_verts<<<dim3((nV + 255) / 256), dim3(256), 0, stream>>>(
        verts, Km, Rm, tv, sx, sy, sz, nV);
    k_prep_faces<<<dim3((nF + 255) / 256), dim3(256), 0, stream>>>(
        faces, sx, sy, sz, rec, box, nF);
    k_zinit<<<dim3((P + 255) / 256), dim3(256), 0, stream>>>(zwin, P);

    int tilesX = (W + 7) / 8, tilesY = (H + 7) / 8;
    int nTiles = tilesX * tilesY;
    dim3 g((nTiles + 3) / 4, (nF + SEGSZ - 1) / SEGSZ, 1);
    k_raster<<<g, dim3(256), 0, stream>>>(rec, box, zwin, nF, W, H, tilesX, nTiles);
    k_shade<<<dim3((P + 255) / 256), dim3(256), 0, stream>>>(
        rec, zwin, tex, bgc, (float*)d_out, W, H);
}